// Round 12
// baseline (123.624 us; speedup 1.0000x reference)
//
#include <hip/hip_runtime.h>

#define NSEQ 2048
#define DIMM 1024
#define NH   16
#define DH   64

using f32x4 = __attribute__((ext_vector_type(4))) float;
using s16x8 = __attribute__((ext_vector_type(8))) short;
using s16x4 = __attribute__((ext_vector_type(4))) short;

__device__ __forceinline__ short f2bf(float f) {
  union { float f; unsigned u; } a; a.f = f;
  unsigned r = (a.u + 0x7fffu + ((a.u >> 16) & 1u)) >> 16;
  return (short)(unsigned short)r;
}
__device__ __forceinline__ float bf2f(short s) {
  union { float f; unsigned u; } a; a.u = ((unsigned)(unsigned short)s) << 16;
  return a.f;
}
__device__ __forceinline__ unsigned cvtpk_bf16(float lo, float hi) {
  unsigned r;
  asm("v_cvt_pk_bf16_f32 %0, %1, %2" : "=v"(r) : "v"(lo), "v"(hi));
  return r;
}

__device__ __forceinline__ void async_lds16(const void* g, void* l) {
  __builtin_amdgcn_global_load_lds(
      (const __attribute__((address_space(1))) void*)g,
      (__attribute__((address_space(3))) void*)l, 16, 0, 0);
}

__device__ __forceinline__ float wave_sum(float v) {
  v += __shfl_xor(v, 1);  v += __shfl_xor(v, 2);  v += __shfl_xor(v, 4);
  v += __shfl_xor(v, 8);  v += __shfl_xor(v, 16); v += __shfl_xor(v, 32);
  return v;
}

// ---------------- prep: 4 weight transposes + LN(x) + bias-MLP layer0 -------
__global__ __launch_bounds__(256) void prep_k(const float* __restrict__ x,
                                              const float* __restrict__ g_norm,
                                              const float* __restrict__ w0,
                                              const float* __restrict__ b0,
                                              const float* __restrict__ g0,
                                              const float* __restrict__ Wq,
                                              const float* __restrict__ Wkv,
                                              const float* __restrict__ w1,
                                              const float* __restrict__ Wout,
                                              short* __restrict__ xn,
                                              short* __restrict__ h0,
                                              short* __restrict__ wqkvT,
                                              short* __restrict__ w1T,
                                              short* __restrict__ woT) {
  __shared__ float tile[32][33];
  __shared__ float rb[8];
  const int bid = blockIdx.x, t = threadIdx.x;
  if (bid < 3200) {
    const float* W; short* Wt; int N, bx, by;
    if (bid < 1024)      { W = Wq;   Wt = wqkvT;                       N = 1024; bx = bid & 31;          by = bid >> 5; }
    else if (bid < 1152) { W = Wkv;  Wt = wqkvT + (size_t)1024 * 1024; N = 128;  bx = (bid - 1024) & 3;  by = (bid - 1024) >> 2; }
    else if (bid < 2176) { W = w1;   Wt = w1T;                         N = 1024; bx = (bid - 1152) & 31; by = (bid - 1152) >> 5; }
    else                 { W = Wout; Wt = woT;                         N = 1024; bx = (bid - 2176) & 31; by = (bid - 2176) >> 5; }
    const int n0 = bx * 32, k0 = by * 32;
    const int tx = t & 31, ty = t >> 5;
#pragma unroll
    for (int r = 0; r < 32; r += 8)
      tile[ty + r][tx] = W[(size_t)(k0 + ty + r) * N + n0 + tx];
    __syncthreads();
#pragma unroll
    for (int r = 0; r < 32; r += 8)
      Wt[(size_t)(n0 + ty + r) * 1024 + k0 + tx] = f2bf(tile[tx][ty + r]);
    return;
  }
  const bool isln = (bid < 7296);
  const int r = isln ? (bid - 3200) : (bid - 7296);
  float v[4];
  if (isln) {
    float4 xv = *(const float4*)(x + (size_t)r * 1024 + t * 4);
    v[0] = xv.x; v[1] = xv.y; v[2] = xv.z; v[3] = xv.w;
  } else {
    const float p = (float)r;
    float4 wv = *(const float4*)(w0 + t * 4);
    float4 bv = *(const float4*)(b0 + t * 4);
    v[0] = p * wv.x + bv.x; v[1] = p * wv.y + bv.y;
    v[2] = p * wv.z + bv.z; v[3] = p * wv.w + bv.w;
  }
  float s  = v[0] + v[1] + v[2] + v[3];
  float ss = v[0]*v[0] + v[1]*v[1] + v[2]*v[2] + v[3]*v[3];
  s = wave_sum(s); ss = wave_sum(ss);
  const int w = t >> 6, ln = t & 63;
  if (ln == 0) { rb[w] = s; rb[4 + w] = ss; }
  __syncthreads();
  s  = rb[0] + rb[1] + rb[2] + rb[3];
  ss = rb[4] + rb[5] + rb[6] + rb[7];
  const float mean = s * (1.f / 1024.f);
  const float inv  = rsqrtf(ss * (1.f / 1024.f) - mean * mean + 1e-5f);
  const float* gp = isln ? g_norm : g0;
  float4 gx = *(const float4*)(gp + t * 4);
  float gg[4] = {gx.x, gx.y, gx.z, gx.w};
  s16x4 o;
#pragma unroll
  for (int j = 0; j < 4; j++) {
    float y = (v[j] - mean) * inv * gg[j];
    if (!isln) y = y / (1.f + __expf(-y));
    o[j] = f2bf(y);
  }
  short* dst = isln ? xn : h0;
  *(s16x4*)(dst + (size_t)r * 1024 + t * 4) = o;
}

// ---------------- btab: LN+silu of h1t rows fused with @ w2 + b2 ------------
__global__ __launch_bounds__(256) void btab_k(const float* __restrict__ h1t,
                                              const float* __restrict__ g1,
                                              const float* __restrict__ w2,
                                              const float* __restrict__ b2,
                                              float* __restrict__ btab) {
  __shared__ float hs[1024];
  __shared__ float rb[8];
  __shared__ float red[256];
  const int r = blockIdx.x, t = threadIdx.x;
  float4 xv = *(const float4*)(h1t + (size_t)r * 1024 + t * 4);
  float v[4] = {xv.x, xv.y, xv.z, xv.w};
  float s  = v[0] + v[1] + v[2] + v[3];
  float ss = v[0]*v[0] + v[1]*v[1] + v[2]*v[2] + v[3]*v[3];
  s = wave_sum(s); ss = wave_sum(ss);
  const int w = t >> 6, ln = t & 63;
  if (ln == 0) { rb[w] = s; rb[4 + w] = ss; }
  __syncthreads();
  s  = rb[0] + rb[1] + rb[2] + rb[3];
  ss = rb[4] + rb[5] + rb[6] + rb[7];
  const float mean = s * (1.f / 1024.f);
  const float inv  = rsqrtf(ss * (1.f / 1024.f) - mean * mean + 1e-5f);
  float4 gx = *(const float4*)(g1 + t * 4);
  float gg[4] = {gx.x, gx.y, gx.z, gx.w};
#pragma unroll
  for (int j = 0; j < 4; j++) {
    float y = (v[j] - mean) * inv * gg[j];
    hs[t * 4 + j] = y / (1.f + __expf(-y));
  }
  __syncthreads();
  const int n = t & 15, ck = t >> 4;
  float acc = 0.f;
  const float* hrow = hs + ck * 64;
  const float* wcol = w2 + (size_t)(ck * 64) * 16 + n;
#pragma unroll 8
  for (int k = 0; k < 64; k++) acc += hrow[k] * wcol[k * 16];
  red[t] = acc;
  __syncthreads();
  if (t < 16) {
    float s2 = 0.f;
#pragma unroll
    for (int c = 0; c < 16; c++) s2 += red[c * 16 + t];
    btab[(size_t)t * NSEQ + r] = s2 + b2[t];
  }
}

// ---------------- per-head static max + pre-scaled bias table (bf16 out) ----
__global__ __launch_bounds__(256) void bmax_k(const float* __restrict__ btab,
                                              const float* __restrict__ nbias,
                                              unsigned short* __restrict__ btab2,
                                              float* __restrict__ mh) {
  const int h = blockIdx.x, t = threadIdx.x;
  const float* src = btab + (size_t)h * 2048;
  float mx = -3e38f;
  for (int j = t; j < 2048; j += 256) mx = fmaxf(mx, src[j]);
  mx = fmaxf(mx, __shfl_xor(mx, 1));  mx = fmaxf(mx, __shfl_xor(mx, 2));
  mx = fmaxf(mx, __shfl_xor(mx, 4));  mx = fmaxf(mx, __shfl_xor(mx, 8));
  mx = fmaxf(mx, __shfl_xor(mx, 16)); mx = fmaxf(mx, __shfl_xor(mx, 32));
  __shared__ float red[4];
  if ((t & 63) == 0) red[t >> 6] = mx;
  __syncthreads();
  float m = fmaxf(fmaxf(red[0], red[1]), fmaxf(red[2], red[3]));
  m = 8.25f + fmaxf(m, nbias[h]);
  if (t == 0) mh[h] = m;
  unsigned short* dst = btab2 + (size_t)h * 2048;
  for (int j = t; j < 2048; j += 256)
    dst[j] = (unsigned short)f2bf((src[j] - m) * 1.44269504f);
}

// ---------------- fused qkv-GEMM + w1-GEMM, 128x64 tiles --------------------
__global__ __launch_bounds__(256, 4) void gemm2_k(const short* __restrict__ xn,
                                                  const short* __restrict__ wqkvT,
                                                  const short* __restrict__ h0,
                                                  const short* __restrict__ w1T,
                                                  float* __restrict__ h1t,
                                                  const float* __restrict__ b1,
                                                  const float* __restrict__ qs,
                                                  const float* __restrict__ ks,
                                                  short* __restrict__ qb,
                                                  short* __restrict__ kb,
                                                  short* __restrict__ vtb) {
  __shared__ __align__(16) short Al[2][128 * 32];   // 16 KB
  __shared__ __align__(16) short Bl[2][64 * 32];    // 8 KB
  const int tid = threadIdx.x;
  const int lane = tid & 63;
  const int l15 = lane & 15, l4 = lane >> 4;
  const int wid = tid >> 6;
  const int bid = blockIdx.x;
  const bool isqkv = bid < 576;
  const short* A; const short* Bm; int rowa0, ct;
  if (isqkv) { A = xn; Bm = wqkvT; rowa0 = (bid & 31) * 128; ct = bid >> 5; }
  else { const int idx = bid - 576; A = h0; Bm = w1T; rowa0 = (idx & 15) * 128; ct = idx >> 4; }
  const int bcol0 = ct * 64;
  const int K = 1024;
  f32x4 acc[2][4];
#pragma unroll
  for (int m = 0; m < 2; m++)
#pragma unroll
    for (int n = 0; n < 4; n++) acc[m][n] = (f32x4){0.f, 0.f, 0.f, 0.f};

  const int sr = tid >> 2, sc = (tid & 3) * 8;
  const short* ga = A  + (size_t)(rowa0 + sr) * K + sc;
  const short* gb = Bm + (size_t)(bcol0 + sr) * K + sc;

  auto stage = [&](int buf, int k0) {
    char* la = (char*)Al[buf] + wid * 1024;
    char* lb = (char*)Bl[buf] + wid * 1024;
    async_lds16(ga + k0,                  la);
    async_lds16(ga + (size_t)64 * K + k0, la + 4096);
    async_lds16(gb + k0,                  lb);
  };

  stage(0, 0);
  int cur = 0;
  for (int k0 = 0; k0 < K; k0 += 32) {
    __syncthreads();
    if (k0 + 32 < K) stage(cur ^ 1, k0 + 32);
    s16x8 af[2], bfr[4];
#pragma unroll
    for (int m = 0; m < 2; m++)
      af[m] = *(const s16x8*)&Al[cur][(wid * 32 + m * 16 + l15) * 32 + l4 * 8];
#pragma unroll
    for (int n = 0; n < 4; n++)
      bfr[n] = *(const s16x8*)&Bl[cur][(n * 16 + l15) * 32 + l4 * 8];
#pragma unroll
    for (int m = 0; m < 2; m++)
#pragma unroll
      for (int n = 0; n < 4; n++)
        acc[m][n] = __builtin_amdgcn_mfma_f32_16x16x32_bf16(af[m], bfr[n], acc[m][n], 0, 0, 0);
    cur ^= 1;
  }

  const int rowg0 = rowa0 + wid * 32;
  if (!isqkv) {
#pragma unroll
    for (int n = 0; n < 4; n++) {
      const int col = bcol0 + n * 16 + l15;
      const float bv = b1[col];
#pragma unroll
      for (int m = 0; m < 2; m++) {
        const int row = rowg0 + m * 16 + l4 * 4;
#pragma unroll
        for (int j = 0; j < 4; j++)
          h1t[(size_t)(row + j) * 1024 + col] = acc[m][n][j] + bv;
      }
    }
  } else if (ct < 17) {
    const bool isq = (ct < 16);
    const float* scp = isq ? qs : ks;
#pragma unroll
    for (int m = 0; m < 2; m++) {
      float inv[4];
#pragma unroll
      for (int jj = 0; jj < 4; jj++) {
        float ssq = 0.f;
#pragma unroll
        for (int n = 0; n < 4; n++) ssq += acc[m][n][jj] * acc[m][n][jj];
        ssq += __shfl_xor(ssq, 1); ssq += __shfl_xor(ssq, 2);
        ssq += __shfl_xor(ssq, 4); ssq += __shfl_xor(ssq, 8);
        inv[jj] = 1.f / fmaxf(sqrtf(ssq), 1e-12f);
      }
#pragma unroll
      for (int n = 0; n < 4; n++) {
        const int d = n * 16 + l15;
        const float sc2 = scp[d];
#pragma unroll
        for (int jj = 0; jj < 4; jj++) {
          const int row = rowg0 + m * 16 + l4 * 4 + jj;
          const short v = f2bf(acc[m][n][jj] * inv[jj] * sc2);
          if (isq) qb[(size_t)row * 1024 + bcol0 + d] = v;
          else     kb[(size_t)row * 64 + d] = v;
        }
      }
    }
  } else {
#pragma unroll
    for (int m = 0; m < 2; m++)
#pragma unroll
      for (int n = 0; n < 4; n++) {
        const int d = n * 16 + l15;
        const int row = rowg0 + m * 16 + l4 * 4;
        const int bb = row >> 11, ii = row & 2047;
        s16x4 o;
#pragma unroll
        for (int jj = 0; jj < 4; jj++) o[jj] = f2bf(acc[m][n][jj]);
        *(s16x4*)(vtb + ((size_t)(bb * 64 + d)) * 2048 + ii) = o;
      }
  }
}

// ---------------- GEMM (out-projection): 128x64 tiles, bf16 out -------------
__global__ __launch_bounds__(256, 4) void gemm_bt(const short* __restrict__ A,
                                                  const short* __restrict__ Bm,
                                                  short* __restrict__ Cb) {
  __shared__ __align__(16) short Al[2][128 * 32];
  __shared__ __align__(16) short Bl[2][64 * 32];
  const int tid = threadIdx.x;
  const int lane = tid & 63;
  const int l15 = lane & 15, l4 = lane >> 4;
  const int wid = tid >> 6;
  const int bid = blockIdx.x;
  const int rowa0 = (bid & 31) * 128, bcol0 = (bid >> 5) * 64;
  const int K = 1024;
  f32x4 acc[2][4];
#pragma unroll
  for (int m = 0; m < 2; m++)
#pragma unroll
    for (int n = 0; n < 4; n++) acc[m][n] = (f32x4){0.f, 0.f, 0.f, 0.f};

  const int sr = tid >> 2, sc = (tid & 3) * 8;
  const short* ga = A  + (size_t)(rowa0 + sr) * K + sc;
  const short* gb = Bm + (size_t)(bcol0 + sr) * K + sc;

  auto stage = [&](int buf, int k0) {
    char* la = (char*)Al[buf] + wid * 1024;
    char* lb = (char*)Bl[buf] + wid * 1024;
    async_lds16(ga + k0,                  la);
    async_lds16(ga + (size_t)64 * K + k0, la + 4096);
    async_lds16(gb + k0,                  lb);
  };

  stage(0, 0);
  int cur = 0;
  for (int k0 = 0; k0 < K; k0 += 32) {
    __syncthreads();
    if (k0 + 32 < K) stage(cur ^ 1, k0 + 32);
    s16x8 af[2], bfr[4];
#pragma unroll
    for (int m = 0; m < 2; m++)
      af[m] = *(const s16x8*)&Al[cur][(wid * 32 + m * 16 + l15) * 32 + l4 * 8];
#pragma unroll
    for (int n = 0; n < 4; n++)
      bfr[n] = *(const s16x8*)&Bl[cur][(n * 16 + l15) * 32 + l4 * 8];
#pragma unroll
    for (int m = 0; m < 2; m++)
#pragma unroll
      for (int n = 0; n < 4; n++)
        acc[m][n] = __builtin_amdgcn_mfma_f32_16x16x32_bf16(af[m], bfr[n], acc[m][n], 0, 0, 0);
    cur ^= 1;
  }
#pragma unroll
  for (int n = 0; n < 4; n++) {
    const int col = bcol0 + n * 16 + l15;
#pragma unroll
    for (int m = 0; m < 2; m++) {
      const int row = rowa0 + wid * 32 + m * 16 + l4 * 4;
#pragma unroll
      for (int j = 0; j < 4; j++)
        Cb[(size_t)(row + j) * 1024 + col] = f2bf(acc[m][n][j]);
    }
  }
}

// ---------------- flash attention v9: r7 straight-line body + bijective swz -
__global__ __launch_bounds__(512, 6) void attn_k(const short* __restrict__ q,
                                                 const short* __restrict__ kk,
                                                 const short* __restrict__ vt,
                                                 const unsigned short* __restrict__ btab2,
                                                 const float* __restrict__ mh,
                                                 const float* __restrict__ nkv,
                                                 const float* __restrict__ nbias,
                                                 const float* __restrict__ kscale,
                                                 short* __restrict__ aout) {
  __shared__ __align__(16) short Kl[2][64 * 64];     // 16 KB swizzled [key][d]
  __shared__ __align__(16) short Vl[2][64 * 64];     // 16 KB swizzled [d][key]
  __shared__ __align__(16) char  Pl[8][1024];        // 8 KB per-wave P
  __shared__ __align__(16) unsigned short btl[2048]; // 4 KB bf16 bias row

  float* nkn = (float*)&Pl[0][0];
  float* nvv = (float*)&Pl[0][256];

  const int tid = threadIdx.x;
  const int w = tid >> 6, lane = tid & 63;
  const int l15 = lane & 15, l4 = lane >> 4;
  const int wq = w & 3, half = w >> 2;
  const int bid = blockIdx.x;
  const int b = bid & 1, h = (bid >> 1) & 15, qt = 31 - (bid >> 5);
  const int i0 = qt * 64;
  const int nt = qt + 1;
  const int qrow0 = i0 + wq * 16;

  if (tid < 256)
    async_lds16(btab2 + (size_t)h * 2048 + tid * 8, (char*)btl + w * 1024);

  const int sr = tid >> 3;
  const int sb = (tid & 7) ^ (sr & 7);
  const short* gk = kk + ((size_t)(b * NSEQ) + sr) * DH + sb * 8;
  const short* gv = vt + ((size_t)b * DH + sr) * NSEQ + sb * 8;

  async_lds16(gk, (char*)Kl[0] + w * 1024);
  async_lds16(gv, (char*)Vl[0] + w * 1024);

  if (w == 0) {
    float kx = nkv[lane];
    float ssn = wave_sum(kx * kx);
    nkn[lane] = kx / fmaxf(sqrtf(ssn), 1e-12f) * kscale[lane];
    nvv[lane] = nkv[64 + lane];
  }
  const short* qbase = q + (size_t)(b * NSEQ + qrow0) * DIMM + h * DH;
  s16x8 qf0 = *(const s16x8*)(qbase + (size_t)l15 * DIMM + l4 * 8);
  s16x8 qf1 = *(const s16x8*)(qbase + (size_t)l15 * DIMM + 32 + l4 * 8);
  const float m = mh[h];
  __syncthreads();

  float den = 0.f;
  f32x4 o[4];
#pragma unroll
  for (int dg = 0; dg < 4; dg++) o[dg] = (f32x4){0.f, 0.f, 0.f, 0.f};
  if (half == 0) {
    float sn = 0.f;
#pragma unroll
    for (int j = 0; j < 8; j++)
      sn += bf2f(qf0[j]) * nkn[l4 * 8 + j] + bf2f(qf1[j]) * nkn[32 + l4 * 8 + j];
    sn += __shfl_xor(sn, 16);
    sn += __shfl_xor(sn, 32);
    const float pnc = __builtin_amdgcn_exp2f(fmaf(sn, 11.5415603f,
                                                  (nbias[h] - m) * 1.44269504f));
    den = pnc;
    float pn[4];
#pragma unroll
    for (int jj = 0; jj < 4; jj++) pn[jj] = __shfl(pnc, l4 * 4 + jj);
#pragma unroll
    for (int dg = 0; dg < 4; dg++) {
      float nv = nvv[dg * 16 + l15];
#pragma unroll
      for (int jj = 0; jj < 4; jj++) o[dg][jj] = pn[jj] * nv;
    }
  }
  __syncthreads();

  char* pw = (char*)Pl[w];
  const int pswz = ((l15 >> 1) & 3) << 4;   // bijective within bank-half
  int cur = 0;

  for (int t = 0; t < nt; ++t) {
    if (t + 1 < nt) {
      const int jn = (t + 1) * 64;
      async_lds16(gk + (size_t)jn * DH, (char*)Kl[cur ^ 1] + w * 1024);
      async_lds16(gv + jn,              (char*)Vl[cur ^ 1] + w * 1024);
    }
    const int j0 = t * 64;
    // swapped QK^T: lane holds P[key = half*32 + kb2*16 + l4*4+jj][q = l15]
    f32x4 s[2];
    s[0] = (f32x4){0.f, 0.f, 0.f, 0.f};
    s[1] = (f32x4){0.f, 0.f, 0.f, 0.f};
#pragma unroll
    for (int c = 0; c < 2; c++) {
#pragma unroll
      for (int kb2 = 0; kb2 < 2; kb2++) {
        const int key = half * 32 + kb2 * 16 + l15;
        s16x8 kf = *(const s16x8*)((const char*)Kl[cur] + key * 128 +
                                   ((((c << 2) + l4) ^ (key & 7)) << 4));
        s[kb2] = __builtin_amdgcn_mfma_f32_16x16x32_bf16(kf, c == 0 ? qf0 : qf1, s[kb2], 0, 0, 0);
      }
    }
    // softmax: unified branch-free path (select + wrap), straight-line body
    float p[2][4];
    float loc = 0.f;
#pragma unroll
    for (int kb2 = 0; kb2 < 2; kb2++) {
#pragma unroll
      for (int jj = 0; jj < 4; jj++) {
        const int rel = (qrow0 + l15) - (j0 + half * 32 + kb2 * 16 + l4 * 4 + jj);
        const float bb = bf2f((short)btl[rel & 2047]);
        const float sv = fmaf(s[kb2][jj], 11.5415603f, bb);
        const float pp = (rel >= 0) ? __builtin_amdgcn_exp2f(sv) : 0.f;
        p[kb2][jj] = pp;
        loc += pp;
      }
    }
    loc += __shfl_xor(loc, 16);
    loc += __shfl_xor(loc, 32);
    den += loc;
    {
      uint2 w0v, w1v;
      w0v.x = cvtpk_bf16(p[0][0], p[0][1]);
      w0v.y = cvtpk_bf16(p[0][2], p[0][3]);
      w1v.x = cvtpk_bf16(p[1][0], p[1][1]);
      w1v.y = cvtpk_bf16(p[1][2], p[1][3]);
      *(uint2*)(pw + l15 * 64 + (((l4 << 3)      ) ^ pswz)) = w0v;
      *(uint2*)(pw + l15 * 64 + (((l4 << 3) + 32 ) ^ pswz)) = w1v;
    }
    s16x8 pf = *(const s16x8*)(pw + l15 * 64 + (((l4 << 4)) ^ pswz));
    {
      const int slice = half * 4 + l4;
#pragma unroll
      for (int dg = 0; dg < 4; dg++) {
        const int d = dg * 16 + l15;
        s16x8 vf = *(const s16x8*)((const char*)Vl[cur] + d * 128 +
                                   ((slice ^ (d & 7)) << 4));
        o[dg] = __builtin_amdgcn_mfma_f32_16x16x32_bf16(pf, vf, o[dg], 0, 0, 0);
      }
    }
    __syncthreads();
    cur ^= 1;
  }

  // ---- combine halves in LDS ----
  if (half == 1) {
    float* st = (float*)Kl + wq * 1024;
#pragma unroll
    for (int dg = 0; dg < 4; dg++)
#pragma unroll
      for (int jj = 0; jj < 4; jj++)
        st[(l4 * 4 + jj) * 64 + dg * 16 + l15] = o[dg][jj];
    if (l4 == 0) ((float*)btl)[wq * 16 + l15] = den;
  }
  __syncthreads();
  if (half == 0) {
    float* st = (float*)Kl + wq * 1024;
    float denj[4];
#pragma unroll
    for (int jj = 0; jj < 4; jj++)
      denj[jj] = __shfl(den, l4 * 4 + jj) + ((float*)btl)[wq * 16 + l4 * 4 + jj];
    float* ob = (float*)Vl + wq * 1024;
#pragma unroll
    for (int dg = 0; dg < 4; dg++)
#pragma unroll
      for (int jj = 0; jj < 4; jj++)
        ob[(l4 * 4 + jj) * 64 + dg * 16 + l15] =
            (o[dg][jj] + st[(l4 * 4 + jj) * 64 + dg * 16 + l15]) / denj[jj];
    const int orow = lane >> 2, oc = (lane & 3) * 16;
    const float* srcp = ob + orow * 64 + oc;
    s16x8 r0, r1;
#pragma unroll
    for (int j = 0; j < 8; j++) { r0[j] = f2bf(srcp[j]); r1[j] = f2bf(srcp[8 + j]); }
    short* gout = aout + (size_t)(b * NSEQ + i0 + wq * 16 + orow) * DIMM + h * DH + oc;
    *(s16x8*)gout = r0;
    *(s16x8*)(gout + 8) = r1;
  }
}

// ---------------- final row LayerNorm (bf16 in, f32 out) --------------------
__global__ __launch_bounds__(256) void final_ln_k(const short* __restrict__ in,
                                                  const float* __restrict__ gamma,
                                                  float* __restrict__ of) {
  const int r = blockIdx.x, t = threadIdx.x;
  s16x4 xb = *(const s16x4*)(in + (size_t)r * 1024 + t * 4);
  float v[4] = {bf2f(xb[0]), bf2f(xb[1]), bf2f(xb[2]), bf2f(xb[3])};
  float s  = v[0] + v[1] + v[2] + v[3];
  float ss = v[0]*v[0] + v[1]*v[1] + v[2]*v[2] + v[3]*v[3];
  s = wave_sum(s); ss = wave_sum(ss);
  __shared__ float rb[8];
  const int w = t >> 6, ln = t & 63;
  if (ln == 0) { rb[w] = s; rb[4 + w] = ss; }
  __syncthreads();
  s  = rb[0] + rb[1] + rb[2] + rb[3];
  ss = rb[4] + rb[5] + rb[6] + rb[7];
  const float mean = s * (1.f / 1024.f);
  const float inv  = rsqrtf(ss * (1.f / 1024.f) - mean * mean + 1e-5f);
  float4 gx = *(const float4*)(gamma + t * 4);
  float4 o;
  o.x = (v[0] - mean) * inv * gx.x;
  o.y = (v[1] - mean) * inv * gx.y;
  o.z = (v[2] - mean) * inv * gx.z;
  o.w = (v[3] - mean) * inv * gx.w;
  *(float4*)(of + (size_t)r * 1024 + t * 4) = o;
}

// ---------------------------------------------------------------------------
extern "C" void kernel_launch(void* const* d_in, const int* in_sizes, int n_in,
                              void* d_out, int out_size, void* d_ws, size_t ws_size,
                              hipStream_t stream) {
  const float* x       = (const float*)d_in[0];
  const float* g_norm  = (const float*)d_in[2];
  const float* Wq      = (const float*)d_in[3];
  const float* Wkv     = (const float*)d_in[4];
  const float* q_scale = (const float*)d_in[5];
  const float* k_scale = (const float*)d_in[6];
  const float* null_kv = (const float*)d_in[7];
  const float* nbias   = (const float*)d_in[8];
  const float* w0      = (const float*)d_in[9];
  const float* b0      = (const float*)d_in[10];
  const float* g0      = (const float*)d_in[11];
  const float* w1      = (const float*)d_in[12];
  const float* b1      = (const float*)d_in[13];
  const float* g1      = (const float*)d_in[14];
  const float* w2      = (const float*)d_in[15];
  const float* b2      = (const float*)d_in[16];
  const float* Wout    = (const float*)d_in[17];
  const float* g_out   = (const float*)d_in[18];

  char* p = (char*)d_ws;
  auto alloc = [&](size_t bytes) {
    char* r = p; p += (bytes + 255) & ~(size_t)255; return r;
  };
  short* xn     = (short*)alloc((size_t)4096 * 1024 * 2);
  short* wqkvT  = (short*)alloc((size_t)1152 * 1024 * 2);
  short* w1T    = (short*)alloc((size_t)1024 * 1024 * 2);
  short* woT    = (short*)alloc((size_t)1024 * 1024 * 2);
  short* qb     = (short*)alloc((size_t)4096 * 1024 * 2);
  short* kbuf   = (short*)alloc((size_t)2 * NSEQ * DH * 2);
  short* vtb    = (short*)alloc((size_t)2 * DH * NSEQ * 2);
  short* h0     = (short*)alloc((size_t)2048 * 1024 * 2);
  float* btab   = (float*)alloc((size_t)16 * NSEQ * 4);
  unsigned short* btab2 = (unsigned short*)alloc((size_t)16 * NSEQ * 2);
  float* mh     = (float*)alloc(16 * 4);
  float* opre   = (float*)alloc((size_t)4096 * 1024 * 4);
  // time-sliced aliases:
  float* h1t    = opre;            // bias-MLP h1 pre-LN (dead before out-proj)
  short* aout   = xn;              // attn output (xn dead after qkv gemm)
  short* opre_b = (short*)opre;    // out-proj bf16 result (h1t dead by then)

  prep_k<<<9344, 256, 0, stream>>>(x, g_norm, w0, b0, g0, Wq, Wkv, w1, Wout,
                                   xn, h0, wqkvT, w1T, woT);
  gemm2_k<<<832, 256, 0, stream>>>(xn, wqkvT, h0, w1T, h1t, b1,
                                   q_scale, k_scale, qb, kbuf, vtb);
  btab_k<<<2048, 256, 0, stream>>>(h1t, g1, w2, b2, btab);
  bmax_k<<<16, 256, 0, stream>>>(btab, nbias, btab2, mh);
  attn_k<<<dim3(1024), 512, 0, stream>>>(qb, kbuf, vtb, btab2, mh, null_kv, nbias,
                                         k_scale, aout);
  gemm_bt<<<512, 256, 0, stream>>>(aout, woT, opre_b);
  final_ln_k<<<4096, 256, 0, stream>>>(opre_b, g_out, (float*)d_out);
}

// Round 13
// 123.415 us; speedup vs baseline: 1.0017x; 1.0017x over previous
//
#include <hip/hip_runtime.h>

#define NSEQ 2048
#define DIMM 1024
#define NH   16
#define DH   64

using f32x4 = __attribute__((ext_vector_type(4))) float;
using s16x8 = __attribute__((ext_vector_type(8))) short;
using s16x4 = __attribute__((ext_vector_type(4))) short;

__device__ __forceinline__ short f2bf(float f) {
  union { float f; unsigned u; } a; a.f = f;
  unsigned r = (a.u + 0x7fffu + ((a.u >> 16) & 1u)) >> 16;
  return (short)(unsigned short)r;
}
__device__ __forceinline__ float bf2f(short s) {
  union { float f; unsigned u; } a; a.u = ((unsigned)(unsigned short)s) << 16;
  return a.f;
}
__device__ __forceinline__ unsigned cvtpk_bf16(float lo, float hi) {
  unsigned r;
  asm("v_cvt_pk_bf16_f32 %0, %1, %2" : "=v"(r) : "v"(lo), "v"(hi));
  return r;
}

__device__ __forceinline__ void async_lds16(const void* g, void* l) {
  __builtin_amdgcn_global_load_lds(
      (const __attribute__((address_space(1))) void*)g,
      (__attribute__((address_space(3))) void*)l, 16, 0, 0);
}

__device__ __forceinline__ float wave_sum(float v) {
  v += __shfl_xor(v, 1);  v += __shfl_xor(v, 2);  v += __shfl_xor(v, 4);
  v += __shfl_xor(v, 8);  v += __shfl_xor(v, 16); v += __shfl_xor(v, 32);
  return v;
}

// ---------------- prep: 4 weight transposes + LN(x) + bias-MLP layer0 -------
__global__ __launch_bounds__(256) void prep_k(const float* __restrict__ x,
                                              const float* __restrict__ g_norm,
                                              const float* __restrict__ w0,
                                              const float* __restrict__ b0,
                                              const float* __restrict__ g0,
                                              const float* __restrict__ Wq,
                                              const float* __restrict__ Wkv,
                                              const float* __restrict__ w1,
                                              const float* __restrict__ Wout,
                                              short* __restrict__ xn,
                                              short* __restrict__ h0,
                                              short* __restrict__ wqkvT,
                                              short* __restrict__ w1T,
                                              short* __restrict__ woT) {
  __shared__ float tile[32][33];
  __shared__ float rb[8];
  const int bid = blockIdx.x, t = threadIdx.x;
  if (bid < 3200) {
    const float* W; short* Wt; int N, bx, by;
    if (bid < 1024)      { W = Wq;   Wt = wqkvT;                       N = 1024; bx = bid & 31;          by = bid >> 5; }
    else if (bid < 1152) { W = Wkv;  Wt = wqkvT + (size_t)1024 * 1024; N = 128;  bx = (bid - 1024) & 3;  by = (bid - 1024) >> 2; }
    else if (bid < 2176) { W = w1;   Wt = w1T;                         N = 1024; bx = (bid - 1152) & 31; by = (bid - 1152) >> 5; }
    else                 { W = Wout; Wt = woT;                         N = 1024; bx = (bid - 2176) & 31; by = (bid - 2176) >> 5; }
    const int n0 = bx * 32, k0 = by * 32;
    const int tx = t & 31, ty = t >> 5;
#pragma unroll
    for (int r = 0; r < 32; r += 8)
      tile[ty + r][tx] = W[(size_t)(k0 + ty + r) * N + n0 + tx];
    __syncthreads();
#pragma unroll
    for (int r = 0; r < 32; r += 8)
      Wt[(size_t)(n0 + ty + r) * 1024 + k0 + tx] = f2bf(tile[tx][ty + r]);
    return;
  }
  const bool isln = (bid < 7296);
  const int r = isln ? (bid - 3200) : (bid - 7296);
  float v[4];
  if (isln) {
    float4 xv = *(const float4*)(x + (size_t)r * 1024 + t * 4);
    v[0] = xv.x; v[1] = xv.y; v[2] = xv.z; v[3] = xv.w;
  } else {
    const float p = (float)r;
    float4 wv = *(const float4*)(w0 + t * 4);
    float4 bv = *(const float4*)(b0 + t * 4);
    v[0] = p * wv.x + bv.x; v[1] = p * wv.y + bv.y;
    v[2] = p * wv.z + bv.z; v[3] = p * wv.w + bv.w;
  }
  float s  = v[0] + v[1] + v[2] + v[3];
  float ss = v[0]*v[0] + v[1]*v[1] + v[2]*v[2] + v[3]*v[3];
  s = wave_sum(s); ss = wave_sum(ss);
  const int w = t >> 6, ln = t & 63;
  if (ln == 0) { rb[w] = s; rb[4 + w] = ss; }
  __syncthreads();
  s  = rb[0] + rb[1] + rb[2] + rb[3];
  ss = rb[4] + rb[5] + rb[6] + rb[7];
  const float mean = s * (1.f / 1024.f);
  const float inv  = rsqrtf(ss * (1.f / 1024.f) - mean * mean + 1e-5f);
  const float* gp = isln ? g_norm : g0;
  float4 gx = *(const float4*)(gp + t * 4);
  float gg[4] = {gx.x, gx.y, gx.z, gx.w};
  s16x4 o;
#pragma unroll
  for (int j = 0; j < 4; j++) {
    float y = (v[j] - mean) * inv * gg[j];
    if (!isln) y = y / (1.f + __expf(-y));
    o[j] = f2bf(y);
  }
  short* dst = isln ? xn : h0;
  *(s16x4*)(dst + (size_t)r * 1024 + t * 4) = o;
}

// ---------------- btab: LN+silu of h1 (bf16) rows fused with @ w2 + b2 ------
__global__ __launch_bounds__(256) void btab_k(const short* __restrict__ h1,
                                              const float* __restrict__ g1,
                                              const float* __restrict__ w2,
                                              const float* __restrict__ b2,
                                              float* __restrict__ btab) {
  __shared__ float hs[1024];
  __shared__ float rb[8];
  __shared__ float red[256];
  const int r = blockIdx.x, t = threadIdx.x;
  s16x4 xb = *(const s16x4*)(h1 + (size_t)r * 1024 + t * 4);
  float v[4] = {bf2f(xb[0]), bf2f(xb[1]), bf2f(xb[2]), bf2f(xb[3])};
  float s  = v[0] + v[1] + v[2] + v[3];
  float ss = v[0]*v[0] + v[1]*v[1] + v[2]*v[2] + v[3]*v[3];
  s = wave_sum(s); ss = wave_sum(ss);
  const int w = t >> 6, ln = t & 63;
  if (ln == 0) { rb[w] = s; rb[4 + w] = ss; }
  __syncthreads();
  s  = rb[0] + rb[1] + rb[2] + rb[3];
  ss = rb[4] + rb[5] + rb[6] + rb[7];
  const float mean = s * (1.f / 1024.f);
  const float inv  = rsqrtf(ss * (1.f / 1024.f) - mean * mean + 1e-5f);
  float4 gx = *(const float4*)(g1 + t * 4);
  float gg[4] = {gx.x, gx.y, gx.z, gx.w};
#pragma unroll
  for (int j = 0; j < 4; j++) {
    float y = (v[j] - mean) * inv * gg[j];
    hs[t * 4 + j] = y / (1.f + __expf(-y));
  }
  __syncthreads();
  const int n = t & 15, ck = t >> 4;
  float acc = 0.f;
  const float* hrow = hs + ck * 64;
  const float* wcol = w2 + (size_t)(ck * 64) * 16 + n;
#pragma unroll 8
  for (int k = 0; k < 64; k++) acc += hrow[k] * wcol[k * 16];
  red[t] = acc;
  __syncthreads();
  if (t < 16) {
    float s2 = 0.f;
#pragma unroll
    for (int c = 0; c < 16; c++) s2 += red[c * 16 + t];
    btab[(size_t)t * NSEQ + r] = s2 + b2[t];
  }
}

// ---------------- per-head static max + pre-scaled bias table (bf16 out) ----
__global__ __launch_bounds__(256) void bmax_k(const float* __restrict__ btab,
                                              const float* __restrict__ nbias,
                                              unsigned short* __restrict__ btab2,
                                              float* __restrict__ mh) {
  const int h = blockIdx.x, t = threadIdx.x;
  const float* src = btab + (size_t)h * 2048;
  float mx = -3e38f;
  for (int j = t; j < 2048; j += 256) mx = fmaxf(mx, src[j]);
  mx = fmaxf(mx, __shfl_xor(mx, 1));  mx = fmaxf(mx, __shfl_xor(mx, 2));
  mx = fmaxf(mx, __shfl_xor(mx, 4));  mx = fmaxf(mx, __shfl_xor(mx, 8));
  mx = fmaxf(mx, __shfl_xor(mx, 16)); mx = fmaxf(mx, __shfl_xor(mx, 32));
  __shared__ float red[4];
  if ((t & 63) == 0) red[t >> 6] = mx;
  __syncthreads();
  float m = fmaxf(fmaxf(red[0], red[1]), fmaxf(red[2], red[3]));
  m = 8.25f + fmaxf(m, nbias[h]);
  if (t == 0) mh[h] = m;
  unsigned short* dst = btab2 + (size_t)h * 2048;
  for (int j = t; j < 2048; j += 256)
    dst[j] = (unsigned short)f2bf((src[j] - m) * 1.44269504f);
}

// ---------------- fused qkv-GEMM + w1-GEMM, 128x64 tiles, XCD-swizzled ------
__global__ __launch_bounds__(256, 4) void gemm2_k(const short* __restrict__ xn,
                                                  const short* __restrict__ wqkvT,
                                                  const short* __restrict__ h0,
                                                  const short* __restrict__ w1T,
                                                  short* __restrict__ h1b,
                                                  const float* __restrict__ b1,
                                                  const float* __restrict__ qs,
                                                  const float* __restrict__ ks,
                                                  short* __restrict__ qb,
                                                  short* __restrict__ kb,
                                                  short* __restrict__ vtb) {
  __shared__ __align__(16) short Al[2][128 * 32];   // 16 KB
  __shared__ __align__(16) short Bl[2][64 * 32];    // 8 KB
  const int tid = threadIdx.x;
  const int lane = tid & 63;
  const int l15 = lane & 15, l4 = lane >> 4;
  const int wid = tid >> 6;
  // XCD-aware bijective swizzle: 832 = 8 * 104
  const int bid = (blockIdx.x & 7) * 104 + (blockIdx.x >> 3);
  const bool isqkv = bid < 576;
  const short* A; const short* Bm; int rowa0, ct;
  if (isqkv) { A = xn; Bm = wqkvT; rowa0 = (bid & 31) * 128; ct = bid >> 5; }
  else { const int idx = bid - 576; A = h0; Bm = w1T; rowa0 = (idx & 15) * 128; ct = idx >> 4; }
  const int bcol0 = ct * 64;
  const int K = 1024;
  f32x4 acc[2][4];
#pragma unroll
  for (int m = 0; m < 2; m++)
#pragma unroll
    for (int n = 0; n < 4; n++) acc[m][n] = (f32x4){0.f, 0.f, 0.f, 0.f};

  const int sr = tid >> 2, sc = (tid & 3) * 8;
  const short* ga = A  + (size_t)(rowa0 + sr) * K + sc;
  const short* gb = Bm + (size_t)(bcol0 + sr) * K + sc;

  auto stage = [&](int buf, int k0) {
    char* la = (char*)Al[buf] + wid * 1024;
    char* lb = (char*)Bl[buf] + wid * 1024;
    async_lds16(ga + k0,                  la);
    async_lds16(ga + (size_t)64 * K + k0, la + 4096);
    async_lds16(gb + k0,                  lb);
  };

  stage(0, 0);
  int cur = 0;
  for (int k0 = 0; k0 < K; k0 += 32) {
    __syncthreads();
    if (k0 + 32 < K) stage(cur ^ 1, k0 + 32);
    s16x8 af[2], bfr[4];
#pragma unroll
    for (int m = 0; m < 2; m++)
      af[m] = *(const s16x8*)&Al[cur][(wid * 32 + m * 16 + l15) * 32 + l4 * 8];
#pragma unroll
    for (int n = 0; n < 4; n++)
      bfr[n] = *(const s16x8*)&Bl[cur][(n * 16 + l15) * 32 + l4 * 8];
#pragma unroll
    for (int m = 0; m < 2; m++)
#pragma unroll
      for (int n = 0; n < 4; n++)
        acc[m][n] = __builtin_amdgcn_mfma_f32_16x16x32_bf16(af[m], bfr[n], acc[m][n], 0, 0, 0);
    cur ^= 1;
  }

  const int rowg0 = rowa0 + wid * 32;
  if (!isqkv) {
#pragma unroll
    for (int n = 0; n < 4; n++) {
      const int col = bcol0 + n * 16 + l15;
      const float bv = b1[col];
#pragma unroll
      for (int m = 0; m < 2; m++) {
        const int row = rowg0 + m * 16 + l4 * 4;
#pragma unroll
        for (int j = 0; j < 4; j++)
          h1b[(size_t)(row + j) * 1024 + col] = f2bf(acc[m][n][j] + bv);
      }
    }
  } else if (ct < 17) {
    const bool isq = (ct < 16);
    const float* scp = isq ? qs : ks;
#pragma unroll
    for (int m = 0; m < 2; m++) {
      float inv[4];
#pragma unroll
      for (int jj = 0; jj < 4; jj++) {
        float ssq = 0.f;
#pragma unroll
        for (int n = 0; n < 4; n++) ssq += acc[m][n][jj] * acc[m][n][jj];
        ssq += __shfl_xor(ssq, 1); ssq += __shfl_xor(ssq, 2);
        ssq += __shfl_xor(ssq, 4); ssq += __shfl_xor(ssq, 8);
        inv[jj] = 1.f / fmaxf(sqrtf(ssq), 1e-12f);
      }
#pragma unroll
      for (int n = 0; n < 4; n++) {
        const int d = n * 16 + l15;
        const float sc2 = scp[d];
#pragma unroll
        for (int jj = 0; jj < 4; jj++) {
          const int row = rowg0 + m * 16 + l4 * 4 + jj;
          const short v = f2bf(acc[m][n][jj] * inv[jj] * sc2);
          if (isq) qb[(size_t)row * 1024 + bcol0 + d] = v;
          else     kb[(size_t)row * 64 + d] = v;
        }
      }
    }
  } else {
#pragma unroll
    for (int m = 0; m < 2; m++)
#pragma unroll
      for (int n = 0; n < 4; n++) {
        const int d = n * 16 + l15;
        const int row = rowg0 + m * 16 + l4 * 4;
        const int bb = row >> 11, ii = row & 2047;
        s16x4 o;
#pragma unroll
        for (int jj = 0; jj < 4; jj++) o[jj] = f2bf(acc[m][n][jj]);
        *(s16x4*)(vtb + ((size_t)(bb * 64 + d)) * 2048 + ii) = o;
      }
  }
}

// ---------------- GEMM (out-projection): 128x64 tiles, bf16 out, swizzled ---
__global__ __launch_bounds__(256, 4) void gemm_bt(const short* __restrict__ A,
                                                  const short* __restrict__ Bm,
                                                  short* __restrict__ Cb) {
  __shared__ __align__(16) short Al[2][128 * 32];
  __shared__ __align__(16) short Bl[2][64 * 32];
  const int tid = threadIdx.x;
  const int lane = tid & 63;
  const int l15 = lane & 15, l4 = lane >> 4;
  const int wid = tid >> 6;
  // XCD-aware bijective swizzle: 512 = 8 * 64
  const int bid = (blockIdx.x & 7) * 64 + (blockIdx.x >> 3);
  const int rowa0 = (bid & 31) * 128, bcol0 = (bid >> 5) * 64;
  const int K = 1024;
  f32x4 acc[2][4];
#pragma unroll
  for (int m = 0; m < 2; m++)
#pragma unroll
    for (int n = 0; n < 4; n++) acc[m][n] = (f32x4){0.f, 0.f, 0.f, 0.f};

  const int sr = tid >> 2, sc = (tid & 3) * 8;
  const short* ga = A  + (size_t)(rowa0 + sr) * K + sc;
  const short* gb = Bm + (size_t)(bcol0 + sr) * K + sc;

  auto stage = [&](int buf, int k0) {
    char* la = (char*)Al[buf] + wid * 1024;
    char* lb = (char*)Bl[buf] + wid * 1024;
    async_lds16(ga + k0,                  la);
    async_lds16(ga + (size_t)64 * K + k0, la + 4096);
    async_lds16(gb + k0,                  lb);
  };

  stage(0, 0);
  int cur = 0;
  for (int k0 = 0; k0 < K; k0 += 32) {
    __syncthreads();
    if (k0 + 32 < K) stage(cur ^ 1, k0 + 32);
    s16x8 af[2], bfr[4];
#pragma unroll
    for (int m = 0; m < 2; m++)
      af[m] = *(const s16x8*)&Al[cur][(wid * 32 + m * 16 + l15) * 32 + l4 * 8];
#pragma unroll
    for (int n = 0; n < 4; n++)
      bfr[n] = *(const s16x8*)&Bl[cur][(n * 16 + l15) * 32 + l4 * 8];
#pragma unroll
    for (int m = 0; m < 2; m++)
#pragma unroll
      for (int n = 0; n < 4; n++)
        acc[m][n] = __builtin_amdgcn_mfma_f32_16x16x32_bf16(af[m], bfr[n], acc[m][n], 0, 0, 0);
    cur ^= 1;
  }
#pragma unroll
  for (int n = 0; n < 4; n++) {
    const int col = bcol0 + n * 16 + l15;
#pragma unroll
    for (int m = 0; m < 2; m++) {
      const int row = rowa0 + wid * 32 + m * 16 + l4 * 4;
#pragma unroll
      for (int j = 0; j < 4; j++)
        Cb[(size_t)(row + j) * 1024 + col] = f2bf(acc[m][n][j]);
    }
  }
}

// ---------------- flash attention v12: r9 body + deferred den reduce --------
__global__ __launch_bounds__(512, 6) void attn_k(const short* __restrict__ q,
                                                 const short* __restrict__ kk,
                                                 const short* __restrict__ vt,
                                                 const unsigned short* __restrict__ btab2,
                                                 const float* __restrict__ mh,
                                                 const float* __restrict__ nkv,
                                                 const float* __restrict__ nbias,
                                                 const float* __restrict__ kscale,
                                                 short* __restrict__ aout) {
  __shared__ __align__(16) short Kl[2][64 * 64];     // 16 KB swizzled [key][d]
  __shared__ __align__(16) short Vl[2][64 * 64];     // 16 KB swizzled [d][key]
  __shared__ __align__(16) char  Pl[8][1024];        // 8 KB per-wave P
  __shared__ __align__(16) unsigned short btl[2048]; // 4 KB bf16 bias row

  float* nkn = (float*)&Pl[0][0];
  float* nvv = (float*)&Pl[0][256];

  const int tid = threadIdx.x;
  const int w = tid >> 6, lane = tid & 63;
  const int l15 = lane & 15, l4 = lane >> 4;
  const int wq = w & 3, half = w >> 2;
  const int bid = blockIdx.x;
  const int b = bid & 1, h = (bid >> 1) & 15, qt = 31 - (bid >> 5);
  const int i0 = qt * 64;
  const int nt = qt + 1;
  const int qrow0 = i0 + wq * 16;

  if (tid < 256)
    async_lds16(btab2 + (size_t)h * 2048 + tid * 8, (char*)btl + w * 1024);

  const int sr = tid >> 3;
  const int sb = (tid & 7) ^ (sr & 7);
  const short* gk = kk + ((size_t)(b * NSEQ) + sr) * DH + sb * 8;
  const short* gv = vt + ((size_t)b * DH + sr) * NSEQ + sb * 8;

  async_lds16(gk, (char*)Kl[0] + w * 1024);
  async_lds16(gv, (char*)Vl[0] + w * 1024);

  if (w == 0) {
    float kx = nkv[lane];
    float ssn = wave_sum(kx * kx);
    nkn[lane] = kx / fmaxf(sqrtf(ssn), 1e-12f) * kscale[lane];
    nvv[lane] = nkv[64 + lane];
  }
  const short* qbase = q + (size_t)(b * NSEQ + qrow0) * DIMM + h * DH;
  s16x8 qf0 = *(const s16x8*)(qbase + (size_t)l15 * DIMM + l4 * 8);
  s16x8 qf1 = *(const s16x8*)(qbase + (size_t)l15 * DIMM + 32 + l4 * 8);
  const float m = mh[h];
  __syncthreads();

  float den = 0.f;   // per-lane partial, reduced ONCE after the loop
  float pnc = 0.f;
  f32x4 o[4];
#pragma unroll
  for (int dg = 0; dg < 4; dg++) o[dg] = (f32x4){0.f, 0.f, 0.f, 0.f};
  if (half == 0) {
    float sn = 0.f;
#pragma unroll
    for (int j = 0; j < 8; j++)
      sn += bf2f(qf0[j]) * nkn[l4 * 8 + j] + bf2f(qf1[j]) * nkn[32 + l4 * 8 + j];
    sn += __shfl_xor(sn, 16);
    sn += __shfl_xor(sn, 32);
    pnc = __builtin_amdgcn_exp2f(fmaf(sn, 11.5415603f,
                                      (nbias[h] - m) * 1.44269504f));
    float pn[4];
#pragma unroll
    for (int jj = 0; jj < 4; jj++) pn[jj] = __shfl(pnc, l4 * 4 + jj);
#pragma unroll
    for (int dg = 0; dg < 4; dg++) {
      float nv = nvv[dg * 16 + l15];
#pragma unroll
      for (int jj = 0; jj < 4; jj++) o[dg][jj] = pn[jj] * nv;
    }
  }
  __syncthreads();

  char* pw = (char*)Pl[w];
  const int pswz = ((l15 >> 1) & 3) << 4;   // bijective within bank-half
  int cur = 0;

  for (int t = 0; t < nt; ++t) {
    if (t + 1 < nt) {
      const int jn = (t + 1) * 64;
      async_lds16(gk + (size_t)jn * DH, (char*)Kl[cur ^ 1] + w * 1024);
      async_lds16(gv + jn,              (char*)Vl[cur ^ 1] + w * 1024);
    }
    const int j0 = t * 64;
    // swapped QK^T: lane holds P[key = half*32 + kb2*16 + l4*4+jj][q = l15]
    f32x4 s[2];
    s[0] = (f32x4){0.f, 0.f, 0.f, 0.f};
    s[1] = (f32x4){0.f, 0.f, 0.f, 0.f};
#pragma unroll
    for (int c = 0; c < 2; c++) {
#pragma unroll
      for (int kb2 = 0; kb2 < 2; kb2++) {
        const int key = half * 32 + kb2 * 16 + l15;
        s16x8 kf = *(const s16x8*)((const char*)Kl[cur] + key * 128 +
                                   ((((c << 2) + l4) ^ (key & 7)) << 4));
        s[kb2] = __builtin_amdgcn_mfma_f32_16x16x32_bf16(kf, c == 0 ? qf0 : qf1, s[kb2], 0, 0, 0);
      }
    }
    // softmax: unified branch-free path; den accumulates per-lane only
    float p[2][4];
#pragma unroll
    for (int kb2 = 0; kb2 < 2; kb2++) {
#pragma unroll
      for (int jj = 0; jj < 4; jj++) {
        const int rel = (qrow0 + l15) - (j0 + half * 32 + kb2 * 16 + l4 * 4 + jj);
        const float bb = bf2f((short)btl[rel & 2047]);
        const float sv = fmaf(s[kb2][jj], 11.5415603f, bb);
        const float pp = (rel >= 0) ? __builtin_amdgcn_exp2f(sv) : 0.f;
        p[kb2][jj] = pp;
        den += pp;
      }
    }
    {
      uint2 w0v, w1v;
      w0v.x = cvtpk_bf16(p[0][0], p[0][1]);
      w0v.y = cvtpk_bf16(p[0][2], p[0][3]);
      w1v.x = cvtpk_bf16(p[1][0], p[1][1]);
      w1v.y = cvtpk_bf16(p[1][2], p[1][3]);
      *(uint2*)(pw + l15 * 64 + (((l4 << 3)      ) ^ pswz)) = w0v;
      *(uint2*)(pw + l15 * 64 + (((l4 << 3) + 32 ) ^ pswz)) = w1v;
    }
    s16x8 pf = *(const s16x8*)(pw + l15 * 64 + (((l4 << 4)) ^ pswz));
    {
      const int slice = half * 4 + l4;
#pragma unroll
      for (int dg = 0; dg < 4; dg++) {
        const int d = dg * 16 + l15;
        s16x8 vf = *(const s16x8*)((const char*)Vl[cur] + d * 128 +
                                   ((slice ^ (d & 7)) << 4));
        o[dg] = __builtin_amdgcn_mfma_f32_16x16x32_bf16(pf, vf, o[dg], 0, 0, 0);
      }
    }
    __syncthreads();
    cur ^= 1;
  }

  // deferred cross-lane den reduce (once), then the null-token term
  den += __shfl_xor(den, 16);
  den += __shfl_xor(den, 32);
  if (half == 0) den += pnc;

  // ---- combine halves in LDS ----
  if (half == 1) {
    float* st = (float*)Kl + wq * 1024;
#pragma unroll
    for (int dg = 0; dg < 4; dg++)
#pragma unroll
      for (int jj = 0; jj < 4; jj++)
        st[(l4 * 4 + jj) * 64 + dg * 16 + l15] = o[dg][jj];
    if (l4 == 0) ((float*)btl)[wq * 16 + l15] = den;
  }
  __syncthreads();
  if (half == 0) {
    float* st = (float*)Kl + wq * 1024;
    float denj[4];
#pragma unroll
    for (int jj = 0; jj < 4; jj++)
      denj[jj] = __shfl(den, l4 * 4 + jj) + ((float*)btl)[wq * 16 + l4 * 4 + jj];
    float* ob = (float*)Vl + wq * 1024;
#pragma unroll
    for (int dg = 0; dg < 4; dg++)
#pragma unroll
      for (int jj = 0; jj < 4; jj++)
        ob[(l4 * 4 + jj) * 64 + dg * 16 + l15] =
            (o[dg][jj] + st[(l4 * 4 + jj) * 64 + dg * 16 + l15]) / denj[jj];
    const int orow = lane >> 2, oc = (lane & 3) * 16;
    const float* srcp = ob + orow * 64 + oc;
    s16x8 r0, r1;
#pragma unroll
    for (int j = 0; j < 8; j++) { r0[j] = f2bf(srcp[j]); r1[j] = f2bf(srcp[8 + j]); }
    short* gout = aout + (size_t)(b * NSEQ + i0 + wq * 16 + orow) * DIMM + h * DH + oc;
    *(s16x8*)gout = r0;
    *(s16x8*)(gout + 8) = r1;
  }
}

// ---------------- final row LayerNorm (bf16 in, f32 out) --------------------
__global__ __launch_bounds__(256) void final_ln_k(const short* __restrict__ in,
                                                  const float* __restrict__ gamma,
                                                  float* __restrict__ of) {
  const int r = blockIdx.x, t = threadIdx.x;
  s16x4 xb = *(const s16x4*)(in + (size_t)r * 1024 + t * 4);
  float v[4] = {bf2f(xb[0]), bf2f(xb[1]), bf2f(xb[2]), bf2f(xb[3])};
  float s  = v[0] + v[1] + v[2] + v[3];
  float ss = v[0]*v[0] + v[1]*v[1] + v[2]*v[2] + v[3]*v[3];
  s = wave_sum(s); ss = wave_sum(ss);
  __shared__ float rb[8];
  const int w = t >> 6, ln = t & 63;
  if (ln == 0) { rb[w] = s; rb[4 + w] = ss; }
  __syncthreads();
  s  = rb[0] + rb[1] + rb[2] + rb[3];
  ss = rb[4] + rb[5] + rb[6] + rb[7];
  const float mean = s * (1.f / 1024.f);
  const float inv  = rsqrtf(ss * (1.f / 1024.f) - mean * mean + 1e-5f);
  float4 gx = *(const float4*)(gamma + t * 4);
  float4 o;
  o.x = (v[0] - mean) * inv * gx.x;
  o.y = (v[1] - mean) * inv * gx.y;
  o.z = (v[2] - mean) * inv * gx.z;
  o.w = (v[3] - mean) * inv * gx.w;
  *(float4*)(of + (size_t)r * 1024 + t * 4) = o;
}

// ---------------------------------------------------------------------------
extern "C" void kernel_launch(void* const* d_in, const int* in_sizes, int n_in,
                              void* d_out, int out_size, void* d_ws, size_t ws_size,
                              hipStream_t stream) {
  const float* x       = (const float*)d_in[0];
  const float* g_norm  = (const float*)d_in[2];
  const float* Wq      = (const float*)d_in[3];
  const float* Wkv     = (const float*)d_in[4];
  const float* q_scale = (const float*)d_in[5];
  const float* k_scale = (const float*)d_in[6];
  const float* null_kv = (const float*)d_in[7];
  const float* nbias   = (const float*)d_in[8];
  const float* w0      = (const float*)d_in[9];
  const float* b0      = (const float*)d_in[10];
  const float* g0      = (const float*)d_in[11];
  const float* w1      = (const float*)d_in[12];
  const float* b1      = (const float*)d_in[13];
  const float* g1      = (const float*)d_in[14];
  const float* w2      = (const float*)d_in[15];
  const float* b2      = (const float*)d_in[16];
  const float* Wout    = (const float*)d_in[17];
  const float* g_out   = (const float*)d_in[18];

  char* p = (char*)d_ws;
  auto alloc = [&](size_t bytes) {
    char* r = p; p += (bytes + 255) & ~(size_t)255; return r;
  };
  short* xn     = (short*)alloc((size_t)4096 * 1024 * 2);
  short* wqkvT  = (short*)alloc((size_t)1152 * 1024 * 2);
  short* w1T    = (short*)alloc((size_t)1024 * 1024 * 2);
  short* woT    = (short*)alloc((size_t)1024 * 1024 * 2);
  short* qb     = (short*)alloc((size_t)4096 * 1024 * 2);
  short* kbuf   = (short*)alloc((size_t)2 * NSEQ * DH * 2);
  short* vtb    = (short*)alloc((size_t)2 * DH * NSEQ * 2);
  short* h0     = (short*)alloc((size_t)2048 * 1024 * 2);
  float* btab   = (float*)alloc((size_t)16 * NSEQ * 4);
  unsigned short* btab2 = (unsigned short*)alloc((size_t)16 * NSEQ * 2);
  float* mh     = (float*)alloc(16 * 4);
  float* opre   = (float*)alloc((size_t)4096 * 1024 * 4);
  // time-sliced aliases:
  short* h1b    = (short*)opre;    // bias-MLP h1 pre-LN, bf16 (dead before out-proj)
  short* aout   = xn;              // attn output (xn dead after qkv gemm)
  short* opre_b = (short*)opre;    // out-proj bf16 result (h1b dead by then)

  prep_k<<<9344, 256, 0, stream>>>(x, g_norm, w0, b0, g0, Wq, Wkv, w1, Wout,
                                   xn, h0, wqkvT, w1T, woT);
  gemm2_k<<<832, 256, 0, stream>>>(xn, wqkvT, h0, w1T, h1b, b1,
                                   q_scale, k_scale, qb, kbuf, vtb);
  btab_k<<<2048, 256, 0, stream>>>(h1b, g1, w2, b2, btab);
  bmax_k<<<16, 256, 0, stream>>>(btab, nbias, btab2, mh);
  attn_k<<<dim3(1024), 512, 0, stream>>>(qb, kbuf, vtb, btab2, mh, null_kv, nbias,
                                         k_scale, aout);
  gemm_bt<<<512, 256, 0, stream>>>(aout, woT, opre_b);
  final_ln_k<<<4096, 256, 0, stream>>>(opre_b, g_out, (float*)d_out);
}